// Round 6
// baseline (820.309 us; speedup 1.0000x reference)
//
#include <hip/hip_runtime.h>
#include <hip/hip_cooperative_groups.h>

namespace cg = cooperative_groups;

#define NN 2048
#define HALF 1024
#define CC 128
#define EE 65536
#define CAP 128

typedef unsigned short u16;

__device__ __forceinline__ float sigm(float v){ return 1.0f/(1.0f + __expf(-v)); }

// One GCN propagation: AGG[d][f] = dinv[d]*( dinv[d]*F[d][f] + sum_sparse dinv[s]*F[s][f]
//                                            + [d<1024] sum_r SpRaw[r][d]*dinv[r]*F[r][f] )
// sparse: every block handles row-pair (2b, 2b+1); dense: blocks < 512 handle unit (ct=b&63, rc=b>>6)
__device__ __forceinline__ void layer_phase(
  const float* __restrict__ Sp, const float* __restrict__ F, const float* __restrict__ dinv,
  const int* __restrict__ cnt, const u16* __restrict__ bucket, float* __restrict__ AGG,
  int b, int t)
{
  // ---- sparse + self ----
  {
    int d = b*2 + (t>>7), f = t & 127;
    float dd = dinv[d];
    float acc = dd * F[(size_t)d*CC + f];
    int m = cnt[d]; m = m > CAP ? CAP : m;
    const u16* bk = bucket + d*CAP;
    for (int j=0;j<m;j++){
      int s = bk[j];
      acc = fmaf(dinv[s], F[(size_t)s*CC + f], acc);
    }
    atomicAdd(&AGG[(size_t)d*CC + f], dd*acc);
  }
  // ---- dense (on-the-fly scaled sigmoid matrix) ----
  if (b < 512) {
    int f = t & 127, half = t >> 7;
    int ct = b & 63, rc = b >> 6;
    int dbase = ct*16 + half*8;
    int r0 = rc*128;
    float acc[8];
    #pragma unroll
    for (int j=0;j<8;j++) acc[j] = 0.f;
    #pragma unroll 4
    for (int r=r0; r<r0+128; ++r){
      float fv = F[(size_t)r*CC + f] * dinv[r];
      const float4* sp4 = (const float4*)(Sp + (size_t)r*HALF + dbase);
      float4 s0 = sp4[0], s1 = sp4[1];
      acc[0] = fmaf(s0.x, fv, acc[0]);
      acc[1] = fmaf(s0.y, fv, acc[1]);
      acc[2] = fmaf(s0.z, fv, acc[2]);
      acc[3] = fmaf(s0.w, fv, acc[3]);
      acc[4] = fmaf(s1.x, fv, acc[4]);
      acc[5] = fmaf(s1.y, fv, acc[5]);
      acc[6] = fmaf(s1.z, fv, acc[6]);
      acc[7] = fmaf(s1.w, fv, acc[7]);
    }
    #pragma unroll
    for (int j=0;j<8;j++)
      atomicAdd(&AGG[(size_t)(dbase+j)*CC + f], acc[j]*dinv[dbase+j]);
  }
}

__global__ void __launch_bounds__(256) mega(
  const float* __restrict__ x, const float* __restrict__ my,
  const float* __restrict__ W1, const float* __restrict__ b1,
  const float* __restrict__ Wmu, const float* __restrict__ bmu,
  const float* __restrict__ Wls, const float* __restrict__ bls,
  const int* __restrict__ ei, float* __restrict__ out,
  float* __restrict__ colsum, int* __restrict__ cnt, float* __restrict__ dinv,
  u16* __restrict__ bucket, float* __restrict__ SpRaw,
  float* __restrict__ AGG1, float* __restrict__ AGG2, float* __restrict__ hid)
{
  cg::grid_group grid = cg::this_grid();
  __shared__ float la[8][CC];
  int b = blockIdx.x, t = threadIdx.x;
  int gtid = b*256 + t;

  // ---- P0: zero cnt + colsum ----
  if (gtid < 2048) cnt[gtid] = 0;
  else if (gtid < 3072) colsum[gtid - 2048] = 0.f;
  grid.sync();

  // ---- P1: prep ----
  if (b < 128) {
    // sigmoid of my[:1024,:1024] -> SpRaw (row-major, coalesced) + column sums
    int c0 = t*4;
    float cs0=0.f, cs1=0.f, cs2=0.f, cs3=0.f;
    #pragma unroll 2
    for (int rr=0; rr<8; ++rr){
      int r = b*8 + rr;
      float4 v = *(const float4*)(my + (size_t)r*NN + c0);
      float s0=sigm(v.x), s1=sigm(v.y), s2=sigm(v.z), s3=sigm(v.w);
      *(float4*)(SpRaw + (size_t)r*HALF + c0) = make_float4(s0,s1,s2,s3);
      cs0+=s0; cs1+=s1; cs2+=s2; cs3+=s3;
    }
    atomicAdd(&colsum[c0+0], cs0);
    atomicAdd(&colsum[c0+1], cs1);
    atomicAdd(&colsum[c0+2], cs2);
    atomicAdd(&colsum[c0+3], cs3);
  } else if (b < 384) {
    // bucket the sparse edges by dst
    int e = (b-128)*256 + t;
    int s = ei[e], d = ei[EE + e];
    int slot = atomicAdd(&cnt[d], 1);
    if (slot < CAP) bucket[d*CAP + slot] = (u16)s;
  } else {
    // zero AGG1 and AGG2 (contiguous, 524288 floats)
    int idx = (b-384)*256 + t;                 // 0..163839
    for (int k = idx; k < 2*NN*CC; k += 640*256)
      AGG1[k] = 0.f;
  }
  grid.sync();

  // ---- P2: dinv ----
  if (gtid < NN) {
    float s = 1.0f + (float)cnt[gtid] + (gtid < HALF ? colsum[gtid] : 0.0f);
    dinv[gtid] = rsqrtf(s);
  }
  grid.sync();

  // ---- P3: layer 1 (aggregate x) ----
  layer_phase(SpRaw, x, dinv, cnt, bucket, AGG1, b, t);
  grid.sync();

  // ---- P4: hidden = relu(AGG1 @ W1 + b1) ----
  if (b < 256) {
    int row0 = b*8;
    #pragma unroll
    for (int i=0;i<4;i++){
      int idx = i*256 + t;
      la[idx>>7][idx&127] = AGG1[(size_t)row0*CC + idx];
    }
    __syncthreads();
    int f = t & 127, rh = t >> 7;
    float acc[4];
    float bb = b1[f];
    #pragma unroll
    for (int i=0;i<4;i++) acc[i] = bb;
    #pragma unroll 4
    for (int kk=0;kk<CC;kk++){
      float w = W1[kk*CC + f];
      #pragma unroll
      for (int i=0;i<4;i++) acc[i] = fmaf(la[rh*4+i][kk], w, acc[i]);
    }
    #pragma unroll
    for (int i=0;i<4;i++){
      float v = acc[i];
      hid[(size_t)(row0 + rh*4 + i)*CC + f] = v > 0.f ? v : 0.f;
    }
  }
  grid.sync();

  // ---- P5: layer 2 (aggregate hidden) ----
  layer_phase(SpRaw, hid, dinv, cnt, bucket, AGG2, b, t);
  grid.sync();

  // ---- P6: z = AGG2 @ [Wmu|Wls] + [bmu|bls] -> out ----
  if (b < 256) {
    int row0 = b*8;
    #pragma unroll
    for (int i=0;i<4;i++){
      int idx = i*256 + t;
      la[idx>>7][idx&127] = AGG2[(size_t)row0*CC + idx];
    }
    __syncthreads();
    int f = t & 127, rh = t >> 7;
    const float* W = (f < 64) ? Wmu : Wls;
    int g = f & 63;
    float bb = (f < 64) ? bmu[g] : bls[g];
    size_t obase = (f < 64) ? 0 : (size_t)NN*64;
    float acc[4];
    #pragma unroll
    for (int i=0;i<4;i++) acc[i] = bb;
    #pragma unroll 4
    for (int kk=0;kk<CC;kk++){
      float w = W[kk*64 + g];
      #pragma unroll
      for (int i=0;i<4;i++) acc[i] = fmaf(la[rh*4+i][kk], w, acc[i]);
    }
    #pragma unroll
    for (int i=0;i<4;i++)
      out[obase + (size_t)(row0 + rh*4 + i)*64 + g] = acc[i];
  }
}

extern "C" void kernel_launch(void* const* d_in, const int* in_sizes, int n_in,
                              void* d_out, int out_size, void* d_ws, size_t ws_size,
                              hipStream_t stream)
{
  (void)in_sizes; (void)n_in; (void)out_size; (void)ws_size;
  const float* x   = (const float*)d_in[0];
  const float* my  = (const float*)d_in[1];
  const float* W1  = (const float*)d_in[2];
  const float* b1  = (const float*)d_in[3];
  const float* Wmu = (const float*)d_in[4];
  const float* bmu = (const float*)d_in[5];
  const float* Wls = (const float*)d_in[6];
  const float* bls = (const float*)d_in[7];
  const int*   ei  = (const int*)d_in[8];
  float* out = (float*)d_out;
  char* ws = (char*)d_ws;

  // ws layout (no memset dispatch — zeroing done in-kernel). AGG1/AGG2 contiguous.
  float* colsum = (float*)(ws + 0);        //    4096 B
  int*   cnt    = (int*)  (ws + 4096);     //    8192 B
  float* dinv   = (float*)(ws + 12288);    //    8192 B
  u16*   bucket = (u16*)  (ws + 20480);    //  524288 B
  float* SpRaw  = (float*)(ws + 544768);   // 4194304 B
  float* AGG1   = (float*)(ws + 4739072);  // 1048576 B
  float* AGG2   = (float*)(ws + 5787648);  // 1048576 B (contiguous after AGG1)
  float* hid    = (float*)(ws + 6836224);  // 1048576 B

  void* args[] = {
    (void*)&x, (void*)&my, (void*)&W1, (void*)&b1, (void*)&Wmu, (void*)&bmu,
    (void*)&Wls, (void*)&bls, (void*)&ei, (void*)&out,
    (void*)&colsum, (void*)&cnt, (void*)&dinv, (void*)&bucket, (void*)&SpRaw,
    (void*)&AGG1, (void*)&AGG2, (void*)&hid
  };
  hipLaunchCooperativeKernel((void*)mega, dim3(1024), dim3(256), args, 0, stream);
}

// Round 7
// 348.706 us; speedup vs baseline: 2.3524x; 2.3524x over previous
//
#include <hip/hip_runtime.h>

#define NN 2048
#define HALF 1024
#define CC 128
#define EE 65536
#define CAP 128

typedef unsigned short u16;

__device__ __forceinline__ float sigm(float v){ return 1.0f/(1.0f + __expf(-v)); }

// ---------------- K1: prep
//  blocks [0,128):   SpRaw[r][c]=sigm(my[r][c]) (row-major, coalesced) + colsum atomics
//  blocks [128,384): bucket sparse edges by dst
//  last-finishing block: dinv[i] = rsqrt(1 + cnt[i] + colsum[i])
__global__ __launch_bounds__(256) void k_prep(
    const float* __restrict__ my, const int* __restrict__ ei,
    float* __restrict__ SpRaw, float* __restrict__ colsum,
    int* __restrict__ cnt, u16* __restrict__ bucket,
    int* __restrict__ done, float* __restrict__ dinv)
{
  int b = blockIdx.x, t = threadIdx.x;
  if (b < 128) {
    int c0 = t*4;
    float cs0=0.f, cs1=0.f, cs2=0.f, cs3=0.f;
    #pragma unroll 2
    for (int rr=0; rr<8; ++rr){
      int r = b*8 + rr;
      float4 v = *(const float4*)(my + (size_t)r*NN + c0);
      float s0=sigm(v.x), s1=sigm(v.y), s2=sigm(v.z), s3=sigm(v.w);
      *(float4*)(SpRaw + (size_t)r*HALF + c0) = make_float4(s0,s1,s2,s3);
      cs0+=s0; cs1+=s1; cs2+=s2; cs3+=s3;
    }
    atomicAdd(&colsum[c0+0], cs0);
    atomicAdd(&colsum[c0+1], cs1);
    atomicAdd(&colsum[c0+2], cs2);
    atomicAdd(&colsum[c0+3], cs3);
  } else {
    int e = (b-128)*256 + t;
    int s = ei[e], d = ei[EE + e];
    int slot = atomicAdd(&cnt[d], 1);
    if (slot < CAP) bucket[d*CAP + slot] = (u16)s;
  }

  // ---- last-block computes dinv ----
  __shared__ int lastf;
  __syncthreads();
  if (t == 0) {
    int v = __hip_atomic_fetch_add(done, 1, __ATOMIC_ACQ_REL, __HIP_MEMORY_SCOPE_AGENT);
    lastf = (v == 383) ? 1 : 0;
  }
  __syncthreads();
  if (lastf) {
    for (int i = t; i < NN; i += 256) {
      int c = __hip_atomic_load(&cnt[i], __ATOMIC_RELAXED, __HIP_MEMORY_SCOPE_AGENT);
      float cs = 0.f;
      if (i < HALF)
        cs = __hip_atomic_load(&colsum[i], __ATOMIC_RELAXED, __HIP_MEMORY_SCOPE_AGENT);
      dinv[i] = rsqrtf(1.0f + (float)c + cs);
    }
  }
}

// ---------------- K2: layer1 = full GCN agg of x, fused with hidden = relu(.@W1 + b1)
//  blocks [0,128):   own rows b*8..b*8+7 (d<1024): dense K=1024 + sparse + self -> LDS -> FC
//  blocks [128,640): own rows 1024 + (b-128)*2 .. +1 : sparse + self -> LDS -> FC
__global__ __launch_bounds__(256) void k_layer1(
  const float* __restrict__ SpRaw, const float* __restrict__ x, const float* __restrict__ dinv,
  const int* __restrict__ cnt, const u16* __restrict__ bucket,
  const float* __restrict__ W1, const float* __restrict__ b1, float* __restrict__ hid)
{
  __shared__ float la[8][CC];
  int b = blockIdx.x, t = threadIdx.x;
  int f = t & 127;
  if (b < 128) {
    int h = t >> 7;
    int db = b*8 + h*4;                 // this half owns rows db..db+3
    float acc[4] = {0.f,0.f,0.f,0.f};
    #pragma unroll 4
    for (int r=0; r<HALF; ++r){
      float fv = x[(size_t)r*CC + f] * dinv[r];
      float4 sp = *(const float4*)(SpRaw + (size_t)r*HALF + db);
      acc[0] = fmaf(sp.x, fv, acc[0]);
      acc[1] = fmaf(sp.y, fv, acc[1]);
      acc[2] = fmaf(sp.z, fv, acc[2]);
      acc[3] = fmaf(sp.w, fv, acc[3]);
    }
    #pragma unroll
    for (int i=0;i<4;i++){
      int d = db + i;
      float dd = dinv[d];
      float a = fmaf(dd, x[(size_t)d*CC + f], acc[i]);   // self + dense
      int m = cnt[d]; m = m > CAP ? CAP : m;
      const u16* bk = bucket + d*CAP;
      for (int j=0;j<m;j++){
        int s = bk[j];
        a = fmaf(dinv[s], x[(size_t)s*CC + f], a);
      }
      la[h*4+i][f] = a * dd;
    }
    __syncthreads();
    float o[4];
    float bb = b1[f];
    o[0]=bb; o[1]=bb; o[2]=bb; o[3]=bb;
    #pragma unroll 4
    for (int k=0;k<CC;k++){
      float w = W1[k*CC + f];
      o[0] = fmaf(la[h*4+0][k], w, o[0]);
      o[1] = fmaf(la[h*4+1][k], w, o[1]);
      o[2] = fmaf(la[h*4+2][k], w, o[2]);
      o[3] = fmaf(la[h*4+3][k], w, o[3]);
    }
    #pragma unroll
    for (int i=0;i<4;i++)
      hid[(size_t)(db+i)*CC + f] = o[i] > 0.f ? o[i] : 0.f;
  } else {
    int rloc = t >> 7;
    int d = HALF + (b-128)*2 + rloc;
    float dd = dinv[d];
    float a = dd * x[(size_t)d*CC + f];
    int m = cnt[d]; m = m > CAP ? CAP : m;
    const u16* bk = bucket + d*CAP;
    for (int j=0;j<m;j++){
      int s = bk[j];
      a = fmaf(dinv[s], x[(size_t)s*CC + f], a);
    }
    la[rloc][f] = a * dd;
    __syncthreads();
    float o = b1[f];
    #pragma unroll 4
    for (int k=0;k<CC;k++)
      o = fmaf(la[rloc][k], W1[k*CC + f], o);
    hid[(size_t)d*CC + f] = o > 0.f ? o : 0.f;
  }
}

// ---------------- K3: layer2 = full GCN agg of hid, fused with z = .@[Wmu|Wls] + [bmu|bls]
__global__ __launch_bounds__(256) void k_layer2(
  const float* __restrict__ SpRaw, const float* __restrict__ hid, const float* __restrict__ dinv,
  const int* __restrict__ cnt, const u16* __restrict__ bucket,
  const float* __restrict__ Wmu, const float* __restrict__ bmu,
  const float* __restrict__ Wls, const float* __restrict__ bls,
  float* __restrict__ out)
{
  __shared__ float la[8][CC];
  int b = blockIdx.x, t = threadIdx.x;
  int f = t & 127;
  const float* W = (f < 64) ? Wmu : Wls;
  int g = f & 63;
  float bb = (f < 64) ? bmu[g] : bls[g];
  size_t obase = (f < 64) ? 0 : (size_t)NN*64;
  if (b < 128) {
    int h = t >> 7;
    int db = b*8 + h*4;
    float acc[4] = {0.f,0.f,0.f,0.f};
    #pragma unroll 4
    for (int r=0; r<HALF; ++r){
      float fv = hid[(size_t)r*CC + f] * dinv[r];
      float4 sp = *(const float4*)(SpRaw + (size_t)r*HALF + db);
      acc[0] = fmaf(sp.x, fv, acc[0]);
      acc[1] = fmaf(sp.y, fv, acc[1]);
      acc[2] = fmaf(sp.z, fv, acc[2]);
      acc[3] = fmaf(sp.w, fv, acc[3]);
    }
    #pragma unroll
    for (int i=0;i<4;i++){
      int d = db + i;
      float dd = dinv[d];
      float a = fmaf(dd, hid[(size_t)d*CC + f], acc[i]);
      int m = cnt[d]; m = m > CAP ? CAP : m;
      const u16* bk = bucket + d*CAP;
      for (int j=0;j<m;j++){
        int s = bk[j];
        a = fmaf(dinv[s], hid[(size_t)s*CC + f], a);
      }
      la[h*4+i][f] = a * dd;
    }
    __syncthreads();
    float o[4];
    o[0]=bb; o[1]=bb; o[2]=bb; o[3]=bb;
    #pragma unroll 4
    for (int k=0;k<CC;k++){
      float w = W[k*64 + g];
      o[0] = fmaf(la[h*4+0][k], w, o[0]);
      o[1] = fmaf(la[h*4+1][k], w, o[1]);
      o[2] = fmaf(la[h*4+2][k], w, o[2]);
      o[3] = fmaf(la[h*4+3][k], w, o[3]);
    }
    #pragma unroll
    for (int i=0;i<4;i++)
      out[obase + (size_t)(db+i)*64 + g] = o[i];
  } else {
    int rloc = t >> 7;
    int d = HALF + (b-128)*2 + rloc;
    float dd = dinv[d];
    float a = dd * hid[(size_t)d*CC + f];
    int m = cnt[d]; m = m > CAP ? CAP : m;
    const u16* bk = bucket + d*CAP;
    for (int j=0;j<m;j++){
      int s = bk[j];
      a = fmaf(dinv[s], hid[(size_t)s*CC + f], a);
    }
    la[rloc][f] = a * dd;
    __syncthreads();
    float o = bb;
    #pragma unroll 4
    for (int k=0;k<CC;k++)
      o = fmaf(la[rloc][k], W[k*64 + g], o);
    out[obase + (size_t)d*64 + g] = o;
  }
}

extern "C" void kernel_launch(void* const* d_in, const int* in_sizes, int n_in,
                              void* d_out, int out_size, void* d_ws, size_t ws_size,
                              hipStream_t stream)
{
  (void)in_sizes; (void)n_in; (void)out_size; (void)ws_size;
  const float* x   = (const float*)d_in[0];
  const float* my  = (const float*)d_in[1];
  const float* W1  = (const float*)d_in[2];
  const float* b1  = (const float*)d_in[3];
  const float* Wmu = (const float*)d_in[4];
  const float* bmu = (const float*)d_in[5];
  const float* Wls = (const float*)d_in[6];
  const float* bls = (const float*)d_in[7];
  const int*   ei  = (const int*)d_in[8];
  float* out = (float*)d_out;
  char* ws = (char*)d_ws;

  // ws layout — zeroed prefix (cnt, colsum, done) = 12352 B; total 5.8 MB
  int*   cnt    = (int*)  (ws + 0);        //    8192 B (memset 0)
  float* colsum = (float*)(ws + 8192);     //    4096 B (memset 0)
  int*   done   = (int*)  (ws + 12288);    //      64 B (memset 0)
  float* dinv   = (float*)(ws + 12352);    //    8192 B
  u16*   bucket = (u16*)  (ws + 20544);    //  524288 B
  float* SpRaw  = (float*)(ws + 544832);   // 4194304 B
  float* hid    = (float*)(ws + 4739136);  // 1048576 B

  hipMemsetAsync(ws, 0, 12352, stream);
  k_prep  <<<384, 256, 0, stream>>>(my, ei, SpRaw, colsum, cnt, bucket, done, dinv);
  k_layer1<<<640, 256, 0, stream>>>(SpRaw, x,   dinv, cnt, bucket, W1, b1, hid);
  k_layer2<<<640, 256, 0, stream>>>(SpRaw, hid, dinv, cnt, bucket, Wmu, bmu, Wls, bls, out);
}